// Round 1
// baseline (398.441 us; speedup 1.0000x reference)
//
#include <hip/hip_runtime.h>
#include <stdint.h>

typedef unsigned short u16;
typedef __bf16 bf16x8 __attribute__((ext_vector_type(8)));
typedef float  f32x4  __attribute__((ext_vector_type(4)));

// ---- problem constants ----
#define SDIM 2048
#define BDIM 8
#define DIN  1024
#define DOUT 4096
#define EDIM 8
#define RDIM 16
#define KAUG 1152            // DIN + E*R
#define MDIM (SDIM*BDIM)     // 16384
#define SCH  32              // s-chunks for the x reduction

__device__ __forceinline__ u16 f2bf(float f) {
    __bf16 h = (__bf16)f;                       // RNE fptrunc
    return __builtin_bit_cast(u16, h);
}

__device__ __forceinline__ void gload16(const u16* g, u16* lds) {
    __builtin_amdgcn_global_load_lds(
        (const __attribute__((address_space(1))) void*)g,
        (__attribute__((address_space(3))) void*)lds, 16, 0, 0);
}

// ---------------------------------------------------------------------------
// k1: per-(b, s-chunk) partial sums of x over s  +  bf16 convert into Xb
// grid (BDIM, SCH), block 256. Each thread owns 4 consecutive i (float4).
// ---------------------------------------------------------------------------
__global__ __launch_bounds__(256) void k1_reduce_convert(
    const float* __restrict__ x, u16* __restrict__ Xb, float* __restrict__ P)
{
    const int b  = blockIdx.x;
    const int sc = blockIdx.y;
    const int i  = threadIdx.x * 4;
    float a0 = 0.f, a1 = 0.f, a2 = 0.f, a3 = 0.f;
    const int s0 = sc * (SDIM / SCH);
    for (int s = s0; s < s0 + (SDIM / SCH); ++s) {
        const float4 v = *reinterpret_cast<const float4*>(
            &x[((size_t)s * BDIM + b) * DIN + i]);
        a0 += v.x; a1 += v.y; a2 += v.z; a3 += v.w;
        ushort4 u{f2bf(v.x), f2bf(v.y), f2bf(v.z), f2bf(v.w)};
        *reinterpret_cast<ushort4*>(&Xb[((size_t)s * BDIM + b) * KAUG + i]) = u;
    }
    float4 p{a0, a1, a2, a3};
    *reinterpret_cast<float4*>(&P[((size_t)sc * BDIM + b) * DIN + i]) = p;
}

// ---------------------------------------------------------------------------
// k2: gate weights g[b,e] = (sum_s x[s,b,:]) . gate_w[e,:] / S + gate_b[e]
// grid (EDIM, BDIM), block 256
// ---------------------------------------------------------------------------
__global__ __launch_bounds__(256) void k2_gates(
    const float* __restrict__ P, const float* __restrict__ gw,
    const float* __restrict__ gb, float* __restrict__ g)
{
    const int e = blockIdx.x, b = blockIdx.y, t = threadIdx.x;
    float dot = 0.f;
    for (int i = t; i < DIN; i += 256) {
        float xs = 0.f;
        #pragma unroll
        for (int c = 0; c < SCH; ++c) xs += P[((size_t)c * BDIM + b) * DIN + i];
        dot += xs * gw[(size_t)e * DIN + i];
    }
    __shared__ float red[256];
    red[t] = dot;
    __syncthreads();
    #pragma unroll
    for (int off = 128; off > 0; off >>= 1) {
        if (t < off) red[t] += red[t + off];
        __syncthreads();
    }
    if (t == 0) g[b * EDIM + e] = red[0] * (1.0f / SDIM) + gb[e];
}

// ---------------------------------------------------------------------------
// kw: build Waug[o][0..1023] = bf16(W[o][i]); Waug[o][1024+e*16+r] = bf16(lora_B[e][o][r])
// grid DOUT, block 256
// ---------------------------------------------------------------------------
__global__ __launch_bounds__(256) void kw_build_waug(
    const float* __restrict__ W, const float* __restrict__ lb, u16* __restrict__ Waug)
{
    const int o = blockIdx.x, t = threadIdx.x;
    for (int i = t; i < DIN; i += 256)
        Waug[(size_t)o * KAUG + i] = f2bf(W[(size_t)o * DIN + i]);
    if (t < EDIM * RDIM) {
        const int e = t >> 4, r = t & 15;
        Waug[(size_t)o * KAUG + DIN + t] =
            f2bf(lb[((size_t)e * DOUT + o) * RDIM + r]);
    }
}

// ---------------------------------------------------------------------------
// kl: lora_A [E][R][DIN] fp32 -> bf16 [128][1024]
// ---------------------------------------------------------------------------
__global__ __launch_bounds__(256) void kl_convert(
    const float* __restrict__ la, u16* __restrict__ LAb)
{
    const int idx = blockIdx.x * 256 + threadIdx.x;
    if (idx < EDIM * RDIM * DIN) LAb[idx] = f2bf(la[idx]);
}

// ---------------------------------------------------------------------------
// k4: u[m][er] = g[b,e] * t[m][er] -> bf16 into Xb cols 1024..1151
// ---------------------------------------------------------------------------
__global__ __launch_bounds__(256) void k4_scale_u(
    const float* __restrict__ T, const float* __restrict__ g, u16* __restrict__ Xb)
{
    const int idx = blockIdx.x * 256 + threadIdx.x;   // MDIM*128 total
    const int m = idx >> 7, er = idx & 127;
    const int b = m & (BDIM - 1), e = er >> 4;
    const float u = g[b * EDIM + e] * T[idx];
    Xb[(size_t)m * KAUG + DIN + er] = f2bf(u);
}

// ---------------------------------------------------------------------------
// gemm_bt: C[M,N] = A[M,K] * B[N,K]^T (+bias), bf16 inputs, fp32 out.
// 128x128 tile, BK=64, 4 waves (2x2, each 64x64 via 4x4 16x16x32 MFMA frags).
// LDS k-slab layout [c][128][8]: conflict-free ds_read_b128 AND linear
// lane-order dest for global_load_lds (per-lane global src, uniform lds base).
// grid (N/128, M/128), block 256.
// ---------------------------------------------------------------------------
template <int ADD_BIAS>
__global__ __launch_bounds__(256) void gemm_bt(
    const u16* __restrict__ A, int lda,
    const u16* __restrict__ B, int ldb,
    float* __restrict__ C, int ldc,
    const float* __restrict__ bias, int ktiles)
{
    __shared__ __align__(16) u16 As[8][128][8];
    __shared__ __align__(16) u16 Bs[8][128][8];

    const int tid  = threadIdx.x;
    const int lane = tid & 63;
    const int l15  = lane & 15;
    const int l4   = lane >> 4;
    const int wid  = tid >> 6;
    const int wr   = wid >> 1;          // wave row (0..1)
    const int wc   = wid & 1;           // wave col (0..1)
    const int m0 = blockIdx.y * 128;
    const int n0 = blockIdx.x * 128;

    const int mr  = tid & 127;          // staging row within tile
    const int chi = tid >> 7;           // staging c low bit

    f32x4 acc[4][4] = {};

    for (int kt = 0; kt < ktiles; ++kt) {
        // ---- stage tiles (8 x global_load_lds_dwordx4 per thread) ----
        #pragma unroll
        for (int q = 0; q < 4; ++q) {
            const int c    = q * 2 + chi;
            const int kofs = kt * 64 + c * 8;
            u16* ldsbase   = (u16*)As + (size_t)(q * 256 + (tid & 192)) * 8;
            gload16(A + (size_t)(m0 + mr) * lda + kofs, ldsbase);
            u16* ldsbaseB  = (u16*)Bs + (size_t)(q * 256 + (tid & 192)) * 8;
            gload16(B + (size_t)(n0 + mr) * ldb + kofs, ldsbaseB);
        }
        __syncthreads();   // compiler drains vmcnt before barrier

        // ---- compute: 32 MFMAs per wave per K-tile ----
        #pragma unroll
        for (int ks = 0; ks < 2; ++ks) {
            const int c = ks * 4 + l4;
            bf16x8 av[4], bv[4];
            #pragma unroll
            for (int mi = 0; mi < 4; ++mi)
                av[mi] = *reinterpret_cast<const bf16x8*>(
                    &As[c][wr * 64 + mi * 16 + l15][0]);
            #pragma unroll
            for (int ni = 0; ni < 4; ++ni)
                bv[ni] = *reinterpret_cast<const bf16x8*>(
                    &Bs[c][wc * 64 + ni * 16 + l15][0]);
            #pragma unroll
            for (int mi = 0; mi < 4; ++mi)
                #pragma unroll
                for (int ni = 0; ni < 4; ++ni)
                    acc[mi][ni] = __builtin_amdgcn_mfma_f32_16x16x32_bf16(
                        av[mi], bv[ni], acc[mi][ni], 0, 0, 0);
        }
        __syncthreads();
    }

    // ---- epilogue: C[row][col], row=(l>>4)*4+reg, col=l&15 per fragment ----
    #pragma unroll
    for (int mi = 0; mi < 4; ++mi) {
        const int r0 = m0 + wr * 64 + mi * 16 + l4 * 4;
        #pragma unroll
        for (int ni = 0; ni < 4; ++ni) {
            const int col = n0 + wc * 64 + ni * 16 + l15;
            const float badd = ADD_BIAS ? bias[col] : 0.0f;
            float* cp = C + (size_t)r0 * ldc + col;
            #pragma unroll
            for (int r = 0; r < 4; ++r)
                cp[(size_t)r * ldc] = acc[mi][ni][r] + badd;
        }
    }
}

// ---------------------------------------------------------------------------
extern "C" void kernel_launch(void* const* d_in, const int* in_sizes, int n_in,
                              void* d_out, int out_size, void* d_ws, size_t ws_size,
                              hipStream_t stream)
{
    const float* x    = (const float*)d_in[0];
    const float* gw   = (const float*)d_in[1];
    const float* gb   = (const float*)d_in[2];
    const float* W    = (const float*)d_in[3];
    const float* bias = (const float*)d_in[4];
    const float* la   = (const float*)d_in[5];
    const float* lb   = (const float*)d_in[6];
    float* out = (float*)d_out;

    // workspace layout (bytes, 256-aligned)
    char* ws = (char*)d_ws;
    u16*   Xb   = (u16*)(ws);                       // 16384*1152*2 = 37,748,736
    u16*   Waug = (u16*)(ws + 37748736);            //  4096*1152*2 =  9,437,184
    float* T    = (float*)(ws + 47185920);          // 16384*128*4  =  8,388,608
    float* P    = (float*)(ws + 55574528);          //  32*8*1024*4 =  1,048,576
    u16*   LAb  = (u16*)(ws + 56623104);            //  128*1024*2  =    262,144
    float* G    = (float*)(ws + 56885248);          //  64*4        =        256

    // 1) reduce x over s (partials) + convert x -> bf16 cols [0,1024)
    k1_reduce_convert<<<dim3(BDIM, SCH), 256, 0, stream>>>(x, Xb, P);
    // 2) build augmented weight, convert lora_A
    kw_build_waug<<<DOUT, 256, 0, stream>>>(W, lb, Waug);
    kl_convert<<<(EDIM * RDIM * DIN + 255) / 256, 256, 0, stream>>>(la, LAb);
    // 3) gate weights
    k2_gates<<<dim3(EDIM, BDIM), 256, 0, stream>>>(P, gw, gb, G);
    // 4) t = Xb(:, :1024) * lora_A^T   [16384 x 128]
    gemm_bt<0><<<dim3(1, MDIM / 128), 256, 0, stream>>>(
        Xb, KAUG, LAb, DIN, T, EDIM * RDIM, nullptr, DIN / 64);
    // 5) u = g * t -> bf16 cols [1024,1152)
    k4_scale_u<<<(MDIM * EDIM * RDIM) / 256, 256, 0, stream>>>(T, G, Xb);
    // 6) out = Xaug * Waug^T + bias
    gemm_bt<1><<<dim3(DOUT / 128, MDIM / 128), 256, 0, stream>>>(
        Xb, KAUG, Waug, KAUG, out, DOUT, bias, KAUG / 64);
}

// Round 2
// 382.453 us; speedup vs baseline: 1.0418x; 1.0418x over previous
//
#include <hip/hip_runtime.h>
#include <stdint.h>

typedef unsigned short u16;
typedef __bf16 bf16x8 __attribute__((ext_vector_type(8)));
typedef float  f32x4  __attribute__((ext_vector_type(4)));

// ---- problem constants ----
#define SDIM 2048
#define BDIM 8
#define DIN  1024
#define DOUT 4096
#define EDIM 8
#define RDIM 16
#define KAUG 1152            // DIN + E*R
#define MDIM (SDIM*BDIM)     // 16384
#define SCH  32

__device__ __forceinline__ u16 f2bf(float f) {
    __bf16 h = (__bf16)f;
    return __builtin_bit_cast(u16, h);
}

__device__ __forceinline__ void gload16(const u16* g, u16* lds) {
    __builtin_amdgcn_global_load_lds(
        (const __attribute__((address_space(1))) void*)g,
        (__attribute__((address_space(3))) void*)lds, 16, 0, 0);
}

// raw barrier with compiler memory fence (no vmcnt(0) drain like __syncthreads)
#define BARF() do { asm volatile("" ::: "memory"); \
                    __builtin_amdgcn_s_barrier();  \
                    asm volatile("" ::: "memory"); } while (0)
#define VMCNT(n) asm volatile("s_waitcnt vmcnt(" #n ")" ::: "memory")

// ---------------------------------------------------------------------------
// k1: per-(b, s-chunk) partial sums of x over s + bf16 convert into Xb
// ---------------------------------------------------------------------------
__global__ __launch_bounds__(256) void k1_reduce_convert(
    const float* __restrict__ x, u16* __restrict__ Xb, float* __restrict__ P)
{
    const int b  = blockIdx.x;
    const int sc = blockIdx.y;
    const int i  = threadIdx.x * 4;
    float a0 = 0.f, a1 = 0.f, a2 = 0.f, a3 = 0.f;
    const int s0 = sc * (SDIM / SCH);
    for (int s = s0; s < s0 + (SDIM / SCH); ++s) {
        const float4 v = *reinterpret_cast<const float4*>(
            &x[((size_t)s * BDIM + b) * DIN + i]);
        a0 += v.x; a1 += v.y; a2 += v.z; a3 += v.w;
        ushort4 u{f2bf(v.x), f2bf(v.y), f2bf(v.z), f2bf(v.w)};
        *reinterpret_cast<ushort4*>(&Xb[((size_t)s * BDIM + b) * KAUG + i]) = u;
    }
    float4 p{a0, a1, a2, a3};
    *reinterpret_cast<float4*>(&P[((size_t)sc * BDIM + b) * DIN + i]) = p;
}

// ---------------------------------------------------------------------------
// k2: gate weights
// ---------------------------------------------------------------------------
__global__ __launch_bounds__(256) void k2_gates(
    const float* __restrict__ P, const float* __restrict__ gw,
    const float* __restrict__ gb, float* __restrict__ g)
{
    const int e = blockIdx.x, b = blockIdx.y, t = threadIdx.x;
    float dot = 0.f;
    for (int i = t; i < DIN; i += 256) {
        float xs = 0.f;
        #pragma unroll
        for (int c = 0; c < SCH; ++c) xs += P[((size_t)c * BDIM + b) * DIN + i];
        dot += xs * gw[(size_t)e * DIN + i];
    }
    __shared__ float red[256];
    red[t] = dot;
    __syncthreads();
    #pragma unroll
    for (int off = 128; off > 0; off >>= 1) {
        if (t < off) red[t] += red[t + off];
        __syncthreads();
    }
    if (t == 0) g[b * EDIM + e] = red[0] * (1.0f / SDIM) + gb[e];
}

// ---------------------------------------------------------------------------
// kw: build Waug
// ---------------------------------------------------------------------------
__global__ __launch_bounds__(256) void kw_build_waug(
    const float* __restrict__ W, const float* __restrict__ lb, u16* __restrict__ Waug)
{
    const int o = blockIdx.x, t = threadIdx.x;
    for (int i = t; i < DIN; i += 256)
        Waug[(size_t)o * KAUG + i] = f2bf(W[(size_t)o * DIN + i]);
    if (t < EDIM * RDIM) {
        const int e = t >> 4, r = t & 15;
        Waug[(size_t)o * KAUG + DIN + t] =
            f2bf(lb[((size_t)e * DOUT + o) * RDIM + r]);
    }
}

__global__ __launch_bounds__(256) void kl_convert(
    const float* __restrict__ la, u16* __restrict__ LAb)
{
    const int idx = blockIdx.x * 256 + threadIdx.x;
    if (idx < EDIM * RDIM * DIN) LAb[idx] = f2bf(la[idx]);
}

__global__ __launch_bounds__(256) void k4_scale_u(
    const float* __restrict__ T, const float* __restrict__ g, u16* __restrict__ Xb)
{
    const int idx = blockIdx.x * 256 + threadIdx.x;
    const int m = idx >> 7, er = idx & 127;
    const int b = m & (BDIM - 1), e = er >> 4;
    const float u = g[b * EDIM + e] * T[idx];
    Xb[(size_t)m * KAUG + DIN + er] = f2bf(u);
}

// ---------------------------------------------------------------------------
// gemm_bt: the R0 128x128 kernel — kept for the small GEMM (N=128 LoRA pass)
// ---------------------------------------------------------------------------
template <int ADD_BIAS>
__global__ __launch_bounds__(256) void gemm_bt(
    const u16* __restrict__ A, int lda,
    const u16* __restrict__ B, int ldb,
    float* __restrict__ C, int ldc,
    const float* __restrict__ bias, int ktiles)
{
    __shared__ __align__(16) u16 As[8][128][8];
    __shared__ __align__(16) u16 Bs[8][128][8];

    const int tid  = threadIdx.x;
    const int lane = tid & 63;
    const int l15  = lane & 15;
    const int l4   = lane >> 4;
    const int wid  = tid >> 6;
    const int wr   = wid >> 1;
    const int wc   = wid & 1;
    const int m0 = blockIdx.y * 128;
    const int n0 = blockIdx.x * 128;
    const int mr  = tid & 127;
    const int chi = tid >> 7;

    f32x4 acc[4][4] = {};

    for (int kt = 0; kt < ktiles; ++kt) {
        #pragma unroll
        for (int q = 0; q < 4; ++q) {
            const int c    = q * 2 + chi;
            const int kofs = kt * 64 + c * 8;
            u16* ldsbase   = (u16*)As + (size_t)(q * 256 + (tid & 192)) * 8;
            gload16(A + (size_t)(m0 + mr) * lda + kofs, ldsbase);
            u16* ldsbaseB  = (u16*)Bs + (size_t)(q * 256 + (tid & 192)) * 8;
            gload16(B + (size_t)(n0 + mr) * ldb + kofs, ldsbaseB);
        }
        __syncthreads();
        #pragma unroll
        for (int ks = 0; ks < 2; ++ks) {
            const int c = ks * 4 + l4;
            bf16x8 av[4], bv[4];
            #pragma unroll
            for (int mi = 0; mi < 4; ++mi)
                av[mi] = *reinterpret_cast<const bf16x8*>(
                    &As[c][wr * 64 + mi * 16 + l15][0]);
            #pragma unroll
            for (int ni = 0; ni < 4; ++ni)
                bv[ni] = *reinterpret_cast<const bf16x8*>(
                    &Bs[c][wc * 64 + ni * 16 + l15][0]);
            #pragma unroll
            for (int mi = 0; mi < 4; ++mi)
                #pragma unroll
                for (int ni = 0; ni < 4; ++ni)
                    acc[mi][ni] = __builtin_amdgcn_mfma_f32_16x16x32_bf16(
                        av[mi], bv[ni], acc[mi][ni], 0, 0, 0);
        }
        __syncthreads();
    }

    #pragma unroll
    for (int mi = 0; mi < 4; ++mi) {
        const int r0 = m0 + wr * 64 + mi * 16 + l4 * 4;
        #pragma unroll
        for (int ni = 0; ni < 4; ++ni) {
            const int col = n0 + wc * 64 + ni * 16 + l15;
            const float badd = ADD_BIAS ? bias[col] : 0.0f;
            float* cp = C + (size_t)r0 * ldc + col;
            #pragma unroll
            for (int r = 0; r < 4; ++r)
                cp[(size_t)r * ldc] = acc[mi][ni][r] + badd;
        }
    }
}

// ---------------------------------------------------------------------------
// gemm256: main GEMM. BM=256,BN=128,BK=64; 512 thr (8 waves, 4x2); ring-3 LDS.
// Counted-vmcnt pipeline (T3/T4): stage K-tile kt+2 while computing kt.
// Per-wave stage insts per K-tile = 6 (A half0, A half1, B; 2 each).
// At the boundary entering K-tile kt, insts newer than kt's last stage:
//   kt+1's 6 + kt+2's A-half0 2 = 8  -> VMCNT(8) guarantees kt fully landed.
// Tail: kt==nt-2 -> VMCNT(6), kt==nt-1 -> VMCNT(0). Never 0 in steady state.
// Buffer-reuse WAR: buf (kt+2)%3 == buf (kt-1)%3; its last reads (K-step kt-1)
// complete (lgkmcnt) before K-step kt-1's final barrier; the first overwrite
// (stage A-half0) is issued after every wave passed that barrier. Safe.
// LDS k-slab layout [c][128][8]: 0 bank conflicts (PMC-verified in R0) and
// linear lane-order dest for global_load_lds.
// ---------------------------------------------------------------------------
__global__ __launch_bounds__(512, 2) void gemm256(
    const u16* __restrict__ A, int lda,
    const u16* __restrict__ B, int ldb,
    float* __restrict__ C, int ldc,
    const float* __restrict__ bias, int nt)
{
    __shared__ __align__(16) u16 shA[3][2][8][128][8];   // 96 KiB
    __shared__ __align__(16) u16 shB[3][8][128][8];      // 48 KiB

    const int tid  = threadIdx.x;
    const int lane = tid & 63;
    const int l15  = lane & 15;
    const int l4   = lane >> 4;
    const int wid  = tid >> 6;      // 0..7
    const int wm   = wid >> 1;      // 0..3  (64-row slice)
    const int wn   = wid & 1;       // 0..1  (64-col slice)
    const int hA   = wm >> 1;       // A half (M)
    const int rA0  = (wm & 1) * 64; // row base within half

    // T1: XCD-aware swizzle (nwg = 2048, % 8 == 0)
    const int f   = blockIdx.x + blockIdx.y * gridDim.x;
    const int cpx = (gridDim.x * gridDim.y) >> 3;
    const int s_  = (f & 7) * cpx + (f >> 3);
    const int bx  = s_ % gridDim.x;
    const int by  = s_ / gridDim.x;
    const int m0  = by * 256;
    const int n0  = bx * 128;

    f32x4  acc[4][4] = {};
    bf16x8 av[4][2], bv[2][2][2];

    auto stA = [&](int kt, int buf, int h) {
        u16* base = &shA[buf][h][0][0][0];
        #pragma unroll
        for (int j = 0; j < 2; ++j) {
            const int cix = j * 512 + tid;           // slab c = cix>>7, row = cix&127
            gload16(A + (size_t)(m0 + h * 128 + (cix & 127)) * lda
                      + kt * 64 + (cix >> 7) * 8,
                    base + cix * 8);
        }
    };
    auto stB = [&](int kt, int buf) {
        u16* base = &shB[buf][0][0][0];
        #pragma unroll
        for (int j = 0; j < 2; ++j) {
            const int cix = j * 512 + tid;
            gload16(B + (size_t)(n0 + (cix & 127)) * ldb
                      + kt * 64 + (cix >> 7) * 8,
                    base + cix * 8);
        }
    };

    // prologue: K-tiles 0 -> buf0, 1 -> buf1 (6 insts each)
    stA(0, 0, 0); stA(0, 0, 1); stB(0, 0);
    stA(1, 1, 0); stA(1, 1, 1); stB(1, 1);

    int cur = 0, stg = 2;
    for (int kt = 0; kt < nt; ++kt) {
        const bool hs = (kt + 2) < nt;

        // ---------------- P0 : cols 0-1 ----------------
        if (hs) stA(kt + 2, stg, 0);
        if (kt < nt - 2)       { VMCNT(8); }
        else if (kt == nt - 2) { VMCNT(6); }
        else                   { VMCNT(0); }
        BARF();   // K-tile kt now valid in buf cur for ALL waves

        #pragma unroll
        for (int r = 0; r < 4; ++r)
            #pragma unroll
            for (int kk = 0; kk < 2; ++kk)
                av[r][kk] = *reinterpret_cast<const bf16x8*>(
                    &shA[cur][hA][kk * 4 + l4][rA0 + r * 16 + l15][0]);
        #pragma unroll
        for (int c = 0; c < 2; ++c)
            #pragma unroll
            for (int kk = 0; kk < 2; ++kk)
                bv[0][c][kk] = *reinterpret_cast<const bf16x8*>(
                    &shB[cur][kk * 4 + l4][wn * 64 + c * 16 + l15][0]);
        if (hs) stA(kt + 2, stg, 1);

        __builtin_amdgcn_s_setprio(1);
        #pragma unroll
        for (int kk = 0; kk < 2; ++kk)
            #pragma unroll
            for (int r = 0; r < 4; ++r)
                #pragma unroll
                for (int c = 0; c < 2; ++c)
                    acc[r][c] = __builtin_amdgcn_mfma_f32_16x16x32_bf16(
                        av[r][kk], bv[0][c][kk], acc[r][c], 0, 0, 0);
        __builtin_amdgcn_s_setprio(0);
        BARF();

        // ---------------- P1 : cols 2-3 ----------------
        #pragma unroll
        for (int c = 0; c < 2; ++c)
            #pragma unroll
            for (int kk = 0; kk < 2; ++kk)
                bv[1][c][kk] = *reinterpret_cast<const bf16x8*>(
                    &shB[cur][kk * 4 + l4][wn * 64 + (2 + c) * 16 + l15][0]);
        if (hs) stB(kt + 2, stg);
        BARF();

        __builtin_amdgcn_s_setprio(1);
        #pragma unroll
        for (int kk = 0; kk < 2; ++kk)
            #pragma unroll
            for (int r = 0; r < 4; ++r)
                #pragma unroll
                for (int c = 0; c < 2; ++c)
                    acc[r][2 + c] = __builtin_amdgcn_mfma_f32_16x16x32_bf16(
                        av[r][kk], bv[1][c][kk], acc[r][2 + c], 0, 0, 0);
        __builtin_amdgcn_s_setprio(0);
        BARF();

        cur = (cur == 2) ? 0 : cur + 1;
        stg = (stg == 2) ? 0 : stg + 1;
    }

    // ---- epilogue ----
    #pragma unroll
    for (int r = 0; r < 4; ++r) {
        const int row0 = m0 + wm * 64 + r * 16 + l4 * 4;
        #pragma unroll
        for (int fc = 0; fc < 4; ++fc) {
            const int col  = n0 + wn * 64 + fc * 16 + l15;
            const float badd = bias[col];
            float* cp = C + (size_t)row0 * ldc + col;
            #pragma unroll
            for (int q = 0; q < 4; ++q)
                cp[(size_t)q * ldc] = acc[r][fc][q] + badd;
        }
    }
}

// ---------------------------------------------------------------------------
extern "C" void kernel_launch(void* const* d_in, const int* in_sizes, int n_in,
                              void* d_out, int out_size, void* d_ws, size_t ws_size,
                              hipStream_t stream)
{
    const float* x    = (const float*)d_in[0];
    const float* gw   = (const float*)d_in[1];
    const float* gb   = (const float*)d_in[2];
    const float* W    = (const float*)d_in[3];
    const float* bias = (const float*)d_in[4];
    const float* la   = (const float*)d_in[5];
    const float* lb   = (const float*)d_in[6];
    float* out = (float*)d_out;

    char* ws = (char*)d_ws;
    u16*   Xb   = (u16*)(ws);                       // 37,748,736 B
    u16*   Waug = (u16*)(ws + 37748736);            //  9,437,184 B
    float* T    = (float*)(ws + 47185920);          //  8,388,608 B
    float* P    = (float*)(ws + 55574528);          //  1,048,576 B
    u16*   LAb  = (u16*)(ws + 56623104);            //    262,144 B
    float* G    = (float*)(ws + 56885248);          //        256 B

    k1_reduce_convert<<<dim3(BDIM, SCH), 256, 0, stream>>>(x, Xb, P);
    kw_build_waug<<<DOUT, 256, 0, stream>>>(W, lb, Waug);
    kl_convert<<<(EDIM * RDIM * DIN + 255) / 256, 256, 0, stream>>>(la, LAb);
    k2_gates<<<dim3(EDIM, BDIM), 256, 0, stream>>>(P, gw, gb, G);
    gemm_bt<0><<<dim3(1, MDIM / 128), 256, 0, stream>>>(
        Xb, KAUG, LAb, DIN, T, EDIM * RDIM, nullptr, DIN / 64);
    k4_scale_u<<<(MDIM * EDIM * RDIM) / 256, 256, 0, stream>>>(T, G, Xb);
    gemm256<<<dim3(DOUT / 128, MDIM / 256), 512, 0, stream>>>(
        Xb, KAUG, Waug, KAUG, out, DOUT, bias, KAUG / 64);
}

// Round 3
// 307.458 us; speedup vs baseline: 1.2959x; 1.2439x over previous
//
#include <hip/hip_runtime.h>
#include <stdint.h>

typedef unsigned short u16;
typedef __bf16 bf16x8 __attribute__((ext_vector_type(8)));
typedef float  f32x4  __attribute__((ext_vector_type(4)));

// ---- problem constants ----
#define SDIM 2048
#define BDIM 8
#define DIN  1024
#define DOUT 4096
#define EDIM 8
#define RDIM 16
#define KAUG 1152            // DIN + E*R
#define MDIM (SDIM*BDIM)     // 16384
#define SCH  32
#define NT   (KAUG/32)       // 36 K-tiles of 32 for the main GEMM

__device__ __forceinline__ u16 f2bf(float f) {
    __bf16 h = (__bf16)f;
    return __builtin_bit_cast(u16, h);
}

__device__ __forceinline__ void gload16(const u16* g, u16* lds) {
    __builtin_amdgcn_global_load_lds(
        (const __attribute__((address_space(1))) void*)g,
        (__attribute__((address_space(3))) void*)lds, 16, 0, 0);
}

#define VMCNT(n)  asm volatile("s_waitcnt vmcnt(" #n ")" ::: "memory")
#define LGKM0()   asm volatile("s_waitcnt lgkmcnt(0)" ::: "memory")

// ---------------------------------------------------------------------------
// k1: per-(b, s-chunk) partial sums of x over s + bf16 convert into Xb
// ---------------------------------------------------------------------------
__global__ __launch_bounds__(256) void k1_reduce_convert(
    const float* __restrict__ x, u16* __restrict__ Xb, float* __restrict__ P)
{
    const int b  = blockIdx.x;
    const int sc = blockIdx.y;
    const int i  = threadIdx.x * 4;
    float a0 = 0.f, a1 = 0.f, a2 = 0.f, a3 = 0.f;
    const int s0 = sc * (SDIM / SCH);
    for (int s = s0; s < s0 + (SDIM / SCH); ++s) {
        const float4 v = *reinterpret_cast<const float4*>(
            &x[((size_t)s * BDIM + b) * DIN + i]);
        a0 += v.x; a1 += v.y; a2 += v.z; a3 += v.w;
        ushort4 u{f2bf(v.x), f2bf(v.y), f2bf(v.z), f2bf(v.w)};
        *reinterpret_cast<ushort4*>(&Xb[((size_t)s * BDIM + b) * KAUG + i]) = u;
    }
    float4 p{a0, a1, a2, a3};
    *reinterpret_cast<float4*>(&P[((size_t)sc * BDIM + b) * DIN + i]) = p;
}

// ---------------------------------------------------------------------------
// k2: gate weights
// ---------------------------------------------------------------------------
__global__ __launch_bounds__(256) void k2_gates(
    const float* __restrict__ P, const float* __restrict__ gw,
    const float* __restrict__ gb, float* __restrict__ g)
{
    const int e = blockIdx.x, b = blockIdx.y, t = threadIdx.x;
    float dot = 0.f;
    for (int i = t; i < DIN; i += 256) {
        float xs = 0.f;
        #pragma unroll
        for (int c = 0; c < SCH; ++c) xs += P[((size_t)c * BDIM + b) * DIN + i];
        dot += xs * gw[(size_t)e * DIN + i];
    }
    __shared__ float red[256];
    red[t] = dot;
    __syncthreads();
    #pragma unroll
    for (int off = 128; off > 0; off >>= 1) {
        if (t < off) red[t] += red[t + off];
        __syncthreads();
    }
    if (t == 0) g[b * EDIM + e] = red[0] * (1.0f / SDIM) + gb[e];
}

// ---------------------------------------------------------------------------
// kw: build Waug
// ---------------------------------------------------------------------------
__global__ __launch_bounds__(256) void kw_build_waug(
    const float* __restrict__ W, const float* __restrict__ lb, u16* __restrict__ Waug)
{
    const int o = blockIdx.x, t = threadIdx.x;
    for (int i = t; i < DIN; i += 256)
        Waug[(size_t)o * KAUG + i] = f2bf(W[(size_t)o * DIN + i]);
    if (t < EDIM * RDIM) {
        const int e = t >> 4, r = t & 15;
        Waug[(size_t)o * KAUG + DIN + t] =
            f2bf(lb[((size_t)e * DOUT + o) * RDIM + r]);
    }
}

__global__ __launch_bounds__(256) void kl_convert(
    const float* __restrict__ la, u16* __restrict__ LAb)
{
    const int idx = blockIdx.x * 256 + threadIdx.x;
    if (idx < EDIM * RDIM * DIN) LAb[idx] = f2bf(la[idx]);
}

__global__ __launch_bounds__(256) void k4_scale_u(
    const float* __restrict__ T, const float* __restrict__ g, u16* __restrict__ Xb)
{
    const int idx = blockIdx.x * 256 + threadIdx.x;
    const int m = idx >> 7, er = idx & 127;
    const int b = m & (BDIM - 1), e = er >> 4;
    const float u = g[b * EDIM + e] * T[idx];
    Xb[(size_t)m * KAUG + DIN + er] = f2bf(u);
}

// ---------------------------------------------------------------------------
// gemm_bt: R0 128x128 kernel — used only for the small LoRA GEMM (N=128)
// ---------------------------------------------------------------------------
template <int ADD_BIAS>
__global__ __launch_bounds__(256) void gemm_bt(
    const u16* __restrict__ A, int lda,
    const u16* __restrict__ B, int ldb,
    float* __restrict__ C, int ldc,
    const float* __restrict__ bias, int ktiles)
{
    __shared__ __align__(16) u16 As[8][128][8];
    __shared__ __align__(16) u16 Bs[8][128][8];

    const int tid  = threadIdx.x;
    const int lane = tid & 63;
    const int l15  = lane & 15;
    const int l4   = lane >> 4;
    const int wid  = tid >> 6;
    const int wr   = wid >> 1;
    const int wc   = wid & 1;
    const int m0 = blockIdx.y * 128;
    const int n0 = blockIdx.x * 128;
    const int mr  = tid & 127;
    const int chi = tid >> 7;

    f32x4 acc[4][4] = {};

    for (int kt = 0; kt < ktiles; ++kt) {
        #pragma unroll
        for (int q = 0; q < 4; ++q) {
            const int c    = q * 2 + chi;
            const int kofs = kt * 64 + c * 8;
            u16* ldsbase   = (u16*)As + (size_t)(q * 256 + (tid & 192)) * 8;
            gload16(A + (size_t)(m0 + mr) * lda + kofs, ldsbase);
            u16* ldsbaseB  = (u16*)Bs + (size_t)(q * 256 + (tid & 192)) * 8;
            gload16(B + (size_t)(n0 + mr) * ldb + kofs, ldsbaseB);
        }
        __syncthreads();
        #pragma unroll
        for (int ks = 0; ks < 2; ++ks) {
            const int c = ks * 4 + l4;
            bf16x8 av[4], bv[4];
            #pragma unroll
            for (int mi = 0; mi < 4; ++mi)
                av[mi] = *reinterpret_cast<const bf16x8*>(
                    &As[c][wr * 64 + mi * 16 + l15][0]);
            #pragma unroll
            for (int ni = 0; ni < 4; ++ni)
                bv[ni] = *reinterpret_cast<const bf16x8*>(
                    &Bs[c][wc * 64 + ni * 16 + l15][0]);
            #pragma unroll
            for (int mi = 0; mi < 4; ++mi)
                #pragma unroll
                for (int ni = 0; ni < 4; ++ni)
                    acc[mi][ni] = __builtin_amdgcn_mfma_f32_16x16x32_bf16(
                        av[mi], bv[ni], acc[mi][ni], 0, 0, 0);
        }
        __syncthreads();
    }

    #pragma unroll
    for (int mi = 0; mi < 4; ++mi) {
        const int r0 = m0 + wr * 64 + mi * 16 + l4 * 4;
        #pragma unroll
        for (int ni = 0; ni < 4; ++ni) {
            const int col = n0 + wc * 64 + ni * 16 + l15;
            const float badd = ADD_BIAS ? bias[col] : 0.0f;
            float* cp = C + (size_t)r0 * ldc + col;
            #pragma unroll
            for (int r = 0; r < 4; ++r)
                cp[(size_t)r * ldc] = acc[mi][ni][r] + badd;
        }
    }
}

// ---------------------------------------------------------------------------
// gemm_main: out = Xaug[16384x1152] * Waug[4096x1152]^T + bias, fp32 out.
// BM=BN=256, BK=32, 512 thr (8 waves 2Mx4N, per-wave 128x64), ring-4 LDS.
// Staging-throughput-bound design: VMEM queue never empties.
//   per K-tile j: S(j+3) -> VMCNT(8) -> lgkm(0) -> s_barrier -> R(j+1) -> MFMA(j)
// vmcnt ledger @ VMCNT of iter j (steady): outstanding = S_{j+2}(4) + S_{j+3}(4)
//   = 8 -> everything older (S_{j+1}) confirmed landed; 8 stay in flight.
// Tails: j==NT-3 -> 4 outstanding; j>=NT-2 -> 0.
// WAR ring proof: S_{j+3} writes buf (j+3)&3 == (j-1)&3; its last reads R_{j-1}
// are drained by the lgkm(0) preceding BAR_{j-1}; S_{j+3} issues after that
// barrier. Reg WAR: operand banks alternate (static even/odd bodies).
// LDS k-slab [buf][slab4][row256][8]: 0 bank conflicts (PMC-verified R0/R1),
// linear lane-order dest for global_load_lds.
// ---------------------------------------------------------------------------
__global__ __launch_bounds__(512) void gemm_main(
    const u16* __restrict__ A, const u16* __restrict__ B,
    float* __restrict__ C, const float* __restrict__ bias)
{
    __shared__ __align__(16) u16 As[4][4][256][8];   // 64 KiB
    __shared__ __align__(16) u16 Bs[4][4][256][8];   // 64 KiB

    const int tid  = threadIdx.x;
    const int lane = tid & 63;
    const int l15  = lane & 15;
    const int l4   = lane >> 4;
    const int wid  = tid >> 6;      // 0..7
    const int wm   = wid >> 2;      // 0..1  (128-row half)
    const int wn   = wid & 3;       // 0..3  (64-col quarter)

    // T1: XCD-aware swizzle (nwg = 16*64 = 1024, % 8 == 0)
    const int f   = blockIdx.x + blockIdx.y * gridDim.x;
    const int cpx = (gridDim.x * gridDim.y) >> 3;
    const int s_  = (f & 7) * cpx + (f >> 3);
    const int m0  = (s_ / gridDim.x) * 256;
    const int n0  = (s_ % gridDim.x) * 256;

    f32x4  acc[8][4] = {};
    bf16x8 av0[8], bv0[4], av1[8], bv1[4];

    auto S = [&](int kt, int buf) {
        u16* baseA = &As[buf][0][0][0];
        u16* baseB = &Bs[buf][0][0][0];
        #pragma unroll
        for (int i = 0; i < 2; ++i) {
            const int cix = i * 512 + tid;           // slab=cix>>8, row=cix&255
            gload16(A + (size_t)(m0 + (cix & 255)) * KAUG + kt * 32 + (cix >> 8) * 8,
                    baseA + cix * 8);
        }
        #pragma unroll
        for (int i = 0; i < 2; ++i) {
            const int cix = i * 512 + tid;
            gload16(B + (size_t)(n0 + (cix & 255)) * KAUG + kt * 32 + (cix >> 8) * 8,
                    baseB + cix * 8);
        }
    };
    auto R = [&](int buf, bf16x8* av, bf16x8* bv) {
        #pragma unroll
        for (int mf = 0; mf < 8; ++mf)
            av[mf] = *reinterpret_cast<const bf16x8*>(
                &As[buf][l4][wm * 128 + mf * 16 + l15][0]);
        #pragma unroll
        for (int nf = 0; nf < 4; ++nf)
            bv[nf] = *reinterpret_cast<const bf16x8*>(
                &Bs[buf][l4][wn * 64 + nf * 16 + l15][0]);
    };
    auto MM = [&](bf16x8* av, bf16x8* bv) {
        __builtin_amdgcn_s_setprio(1);
        #pragma unroll
        for (int mf = 0; mf < 8; ++mf)
            #pragma unroll
            for (int nf = 0; nf < 4; ++nf)
                acc[mf][nf] = __builtin_amdgcn_mfma_f32_16x16x32_bf16(
                    av[mf], bv[nf], acc[mf][nf], 0, 0, 0);
        __builtin_amdgcn_s_setprio(0);
    };

    // prologue: stage tiles 0,1,2 (12 insts); confirm tile 0; read its frags
    S(0, 0); S(1, 1); S(2, 2);
    VMCNT(8);
    __builtin_amdgcn_s_barrier();
    R(0, av0, bv0);

    #define BODY(J, AVc, BVc, AVn, BVn)                                     \
    do {                                                                    \
        if ((J) + 3 < NT) S((J) + 3, ((J) + 3) & 3);                        \
        if ((J) <= NT - 4)      { VMCNT(8); }                               \
        else if ((J) == NT - 3) { VMCNT(4); }                               \
        else                    { VMCNT(0); }                               \
        LGKM0();                                                            \
        __builtin_amdgcn_s_barrier();                                       \
        if ((J) + 1 < NT) R(((J) + 1) & 3, AVn, BVn);                       \
        MM(AVc, BVc);                                                       \
    } while (0)

    for (int j = 0; j < NT; j += 2) {
        BODY(j,     av0, bv0, av1, bv1);
        BODY(j + 1, av1, bv1, av0, bv0);
    }
    #undef BODY

    // ---- epilogue: row=(l>>4)*4+reg, col=l&15 per fragment ----
    #pragma unroll
    for (int mf = 0; mf < 8; ++mf) {
        const int row0 = m0 + wm * 128 + mf * 16 + l4 * 4;
        #pragma unroll
        for (int nf = 0; nf < 4; ++nf) {
            const int col = n0 + wn * 64 + nf * 16 + l15;
            const float badd = bias[col];
            float* cp = C + (size_t)row0 * DOUT + col;
            #pragma unroll
            for (int q = 0; q < 4; ++q)
                cp[(size_t)q * DOUT] = acc[mf][nf][q] + badd;
        }
    }
}

// ---------------------------------------------------------------------------
extern "C" void kernel_launch(void* const* d_in, const int* in_sizes, int n_in,
                              void* d_out, int out_size, void* d_ws, size_t ws_size,
                              hipStream_t stream)
{
    const float* x    = (const float*)d_in[0];
    const float* gw   = (const float*)d_in[1];
    const float* gb   = (const float*)d_in[2];
    const float* W    = (const float*)d_in[3];
    const float* bias = (const float*)d_in[4];
    const float* la   = (const float*)d_in[5];
    const float* lb   = (const float*)d_in[6];
    float* out = (float*)d_out;

    char* ws = (char*)d_ws;
    u16*   Xb   = (u16*)(ws);                       // 37,748,736 B
    u16*   Waug = (u16*)(ws + 37748736);            //  9,437,184 B
    float* T    = (float*)(ws + 47185920);          //  8,388,608 B
    float* P    = (float*)(ws + 55574528);          //  1,048,576 B
    u16*   LAb  = (u16*)(ws + 56623104);            //    262,144 B
    float* G    = (float*)(ws + 56885248);          //        256 B

    k1_reduce_convert<<<dim3(BDIM, SCH), 256, 0, stream>>>(x, Xb, P);
    kw_build_waug<<<DOUT, 256, 0, stream>>>(W, lb, Waug);
    kl_convert<<<(EDIM * RDIM * DIN + 255) / 256, 256, 0, stream>>>(la, LAb);
    k2_gates<<<dim3(EDIM, BDIM), 256, 0, stream>>>(P, gw, gb, G);
    gemm_bt<0><<<dim3(1, MDIM / 128), 256, 0, stream>>>(
        Xb, KAUG, LAb, DIN, T, EDIM * RDIM, nullptr, DIN / 64);
    k4_scale_u<<<(MDIM * EDIM * RDIM) / 256, 256, 0, stream>>>(T, G, Xb);
    gemm_main<<<dim3(DOUT / 256, MDIM / 256), 512, 0, stream>>>(
        Xb, Waug, out, bias);
}